// Round 4
// baseline (947.074 us; speedup 1.0000x reference)
//
#include <hip/hip_runtime.h>
#include <cfloat>
#include <math.h>

#define B_      16
#define N_TOK   1029
#define C_      1024
#define H_      16
#define D_      64
#define PREFIX  5
#define M_ROWS  (B_ * N_TOK)                       // 16464
#define HEAD_SLAB ((size_t)B_ * H_ * N_TOK * D_)   // 16,859,136 floats (= M_ROWS*C_)
#define VT_STRIDE 1088                             // 17*64: padded key dim for V^T slab

typedef __attribute__((ext_vector_type(8))) short bf16x8;
typedef __attribute__((ext_vector_type(4))) float f32x4;

// ---- bf16 helpers (RNE), raw ushort storage ------------------------------
__device__ __forceinline__ unsigned short f2bf(float f) {
    unsigned u = __float_as_uint(f);
    u += 0x7fffu + ((u >> 16) & 1u);          // round-to-nearest-even
    return (unsigned short)(u >> 16);
}
__device__ __forceinline__ float bf2f(unsigned short h) {
    return __uint_as_float(((unsigned)h) << 16);
}

// ---------------------------------------------------------------------------
// Split fp32 array into bf16 hi + bf16 lo (residual). n4 = count/4.
// ---------------------------------------------------------------------------
__global__ __launch_bounds__(256)
void split_kernel(const float* __restrict__ in, unsigned short* __restrict__ hi,
                  unsigned short* __restrict__ lo, int n4)
{
    const int i = blockIdx.x * 256 + threadIdx.x;
    if (i >= n4) return;
    const float4 v = ((const float4*)in)[i];
    ushort4 h, l;
    h.x = f2bf(v.x); l.x = f2bf(v.x - bf2f(h.x));
    h.y = f2bf(v.y); l.y = f2bf(v.y - bf2f(h.y));
    h.z = f2bf(v.z); l.z = f2bf(v.z - bf2f(h.z));
    h.w = f2bf(v.w); l.w = f2bf(v.w - bf2f(h.w));
    ((ushort4*)hi)[i] = h;
    ((ushort4*)lo)[i] = l;
}

// ---------------------------------------------------------------------------
// 3-phase pipelined MFMA GEMM, 256x256 tile, BK=32, 512 threads (8 waves 2Mx4N).
// (UNCHANGED from round-3 passing version.)
// ---------------------------------------------------------------------------
__device__ __forceinline__ bf16x8 frag_ld(const unsigned short* slab, int r, int q) {
    const int L = r >> 1;
    const int s = (q | ((r & 1) << 2)) ^ (L & 7);
    return *(const bf16x8*)(slab + L * 64 + s * 8);
}

#define WAIT_BAR(N) do {                                          \
    asm volatile("s_waitcnt vmcnt(" #N ")" ::: "memory");         \
    __builtin_amdgcn_s_barrier();                                 \
    __builtin_amdgcn_sched_barrier(0);                            \
} while (0)

__global__ __launch_bounds__(512, 2)
void gemm_mfma8(const unsigned short* __restrict__ Ahi, const unsigned short* __restrict__ Alo,
                const unsigned short* __restrict__ Whi, const unsigned short* __restrict__ Wlo,
                const float* __restrict__ bias, float* __restrict__ out,
                int M, int Ncols, int K, int scatter)
{
    __shared__ unsigned short lds[2][4][256 * 32];   // 128 KB: [buf][0=Ahi,1=Alo,2=Bhi,3=Blo]

    const int tid  = threadIdx.x;
    const int wave = tid >> 6;
    const int lane = tid & 63;
    const int lm   = lane & 15;
    const int quad = lane >> 4;
    const int bx = blockIdx.x, by = blockIdx.y;
    const int wm = wave >> 2;          // 0..1  (M half)
    const int wn = wave & 3;           // 0..3  (N quarter)
    const int rowA = by * 256;
    const int rowB = bx * 256;

    f32x4 acc[8][4];
#pragma unroll
    for (int mi = 0; mi < 8; ++mi)
#pragma unroll
        for (int ni = 0; ni < 4; ++ni)
            acc[mi][ni] = (f32x4){0.f, 0.f, 0.f, 0.f};

#define STAGE(buf_, slab_, base_, row0_, doClamp_, k0_) do {                          \
    _Pragma("unroll")                                                                 \
    for (int i_ = 0; i_ < 2; ++i_) {                                                  \
        const int c_ = i_ * 512 + tid;                                                \
        const int L_ = c_ >> 3;                                                       \
        const int u_ = (c_ & 7) ^ (L_ & 7);                                           \
        int grow_ = (row0_) + 2 * L_ + (u_ >> 2);                                     \
        if (doClamp_) grow_ = min(grow_, M - 1);                                      \
        const unsigned short* src_ = (base_) + (size_t)grow_ * K + (k0_) + (u_ & 3) * 8; \
        __builtin_amdgcn_global_load_lds(                                             \
            (__attribute__((address_space(1))) void*)src_,                            \
            (__attribute__((address_space(3))) void*)&lds[buf_][slab_][(i_ * 512 + wave * 64) * 8], \
            16, 0, 0);                                                                \
    }                                                                                 \
} while (0)

    // Prologue: tile 0, issue order {Ahi,Bhi} then {Blo} then {Alo}.
    STAGE(0, 0, Ahi, rowA, true,  0);
    STAGE(0, 2, Whi, rowB, false, 0);
    STAGE(0, 3, Wlo, rowB, false, 0);
    STAGE(0, 1, Alo, rowA, true,  0);

    const int NT = K >> 5;             // K-tiles of BK=32
    for (int t = 0; t < NT; ++t) {
        const int cur = t & 1, nxt = cur ^ 1;
        const int tn = (t + 1 == NT) ? 0 : t + 1;   // wrap-stage: uniform counts
        const int k1 = tn << 5;

        // ---------- P0: acc += Ahi*Bhi ----------
        WAIT_BAR(4);
        STAGE(nxt, 0, Ahi, rowA, true,  k1);
        STAGE(nxt, 2, Whi, rowB, false, k1);
        bf16x8 b[4], a[8];
#pragma unroll
        for (int ni = 0; ni < 4; ++ni)
            b[ni] = frag_ld(&lds[cur][2][0], wn * 64 + ni * 16 + lm, quad);
#pragma unroll
        for (int mi = 0; mi < 8; ++mi)
            a[mi] = frag_ld(&lds[cur][0][0], wm * 128 + mi * 16 + lm, quad);
        __builtin_amdgcn_s_setprio(1);
#pragma unroll
        for (int mi = 0; mi < 8; ++mi)
#pragma unroll
            for (int ni = 0; ni < 4; ++ni)
                acc[mi][ni] = __builtin_amdgcn_mfma_f32_16x16x32_bf16(a[mi], b[ni], acc[mi][ni], 0, 0, 0);
        __builtin_amdgcn_s_setprio(0);

        // ---------- P1: acc += Ahi*Blo ----------
        WAIT_BAR(6);
        STAGE(nxt, 3, Wlo, rowB, false, k1);
        __builtin_amdgcn_s_setprio(1);
#pragma unroll
        for (int ni = 0; ni < 4; ++ni) {
            const bf16x8 bl = frag_ld(&lds[cur][3][0], wn * 64 + ni * 16 + lm, quad);
#pragma unroll
            for (int mi = 0; mi < 8; ++mi)
                acc[mi][ni] = __builtin_amdgcn_mfma_f32_16x16x32_bf16(a[mi], bl, acc[mi][ni], 0, 0, 0);
        }
        __builtin_amdgcn_s_setprio(0);

        // ---------- P2: acc += Alo*Bhi ----------
        WAIT_BAR(6);
        STAGE(nxt, 1, Alo, rowA, true, k1);
        __builtin_amdgcn_s_setprio(1);
#pragma unroll
        for (int mi = 0; mi < 8; ++mi) {
            const bf16x8 al = frag_ld(&lds[cur][1][0], wm * 128 + mi * 16 + lm, quad);
#pragma unroll
            for (int ni = 0; ni < 4; ++ni)
                acc[mi][ni] = __builtin_amdgcn_mfma_f32_16x16x32_bf16(al, b[ni], acc[mi][ni], 0, 0, 0);
        }
        __builtin_amdgcn_s_setprio(0);
    }
#undef STAGE
    asm volatile("s_waitcnt vmcnt(0)" ::: "memory");

    // ---- epilogue: bias + store (direct or QKV scatter) ----
#pragma unroll
    for (int mi = 0; mi < 8; ++mi) {
#pragma unroll
        for (int rr = 0; rr < 4; ++rr) {
            const int gm = rowA + wm * 128 + mi * 16 + quad * 4 + rr;
            if (gm >= M) continue;
            if (!scatter) {
#pragma unroll
                for (int ni = 0; ni < 4; ++ni) {
                    const int gn = rowB + wn * 64 + ni * 16 + lm;
                    out[(size_t)gm * Ncols + gn] = acc[mi][ni][rr] + bias[gn];
                }
            } else {
                const int b_  = gm / N_TOK;
                const int tok = gm - b_ * N_TOK;
#pragma unroll
                for (int ni = 0; ni < 4; ++ni) {
                    const int gn    = rowB + wn * 64 + ni * 16 + lm;
                    const int which = gn >> 10;
                    const int h     = (gn >> 6) & 15;
                    const int d     = gn & 63;
                    const size_t dst = (size_t)which * HEAD_SLAB +
                                       (((size_t)(b_ * H_ + h)) * N_TOK + tok) * 64 + d;
                    out[dst] = acc[mi][ni][rr] + bias[gn];
                }
            }
        }
    }
}
#undef WAIT_BAR

// ---------------------------------------------------------------------------
// RoPE (fp32) + bf16 hi/lo split of q,k into dedicated slabs.
// q gets the 1/sqrt(D)=0.125 score scale folded in.
// ---------------------------------------------------------------------------
__global__ __launch_bounds__(256)
void rope_convert(const float* __restrict__ qf, const float* __restrict__ kf,
                  const float* __restrict__ sin_, const float* __restrict__ cos_,
                  unsigned short* __restrict__ qhi, unsigned short* __restrict__ qlo,
                  unsigned short* __restrict__ khi, unsigned short* __restrict__ klo)
{
    const int idx = blockIdx.x * 256 + threadIdx.x;
    const int total = B_ * H_ * N_TOK * 32;
    if (idx >= total) return;
    const int d   = idx & 31;
    const int tmp = idx >> 5;
    const int n   = tmp % N_TOK;
    const int bh  = tmp / N_TOK;

    const size_t base = ((size_t)bh * N_TOK + n) * 64;
    float q1 = qf[base + d], q2 = qf[base + d + 32];
    float k1 = kf[base + d], k2 = kf[base + d + 32];

    if (n >= PREFIX) {
        const int r = n - PREFIX;
        const float c1 = cos_[r * 64 + d];
        const float c2 = cos_[r * 64 + d + 32];
        const float s1 = sin_[r * 64 + d];
        const float s2 = sin_[r * 64 + d + 32];
        const float nq1 = q1 * c1 - q2 * s1;
        const float nq2 = q2 * c2 + q1 * s2;
        q1 = nq1; q2 = nq2;
        const float nk1 = k1 * c1 - k2 * s1;
        const float nk2 = k2 * c2 + k1 * s2;
        k1 = nk1; k2 = nk2;
    }
    q1 *= 0.125f; q2 *= 0.125f;

    unsigned short h;
    h = f2bf(q1); qhi[base + d]      = h; qlo[base + d]      = f2bf(q1 - bf2f(h));
    h = f2bf(q2); qhi[base + d + 32] = h; qlo[base + d + 32] = f2bf(q2 - bf2f(h));
    h = f2bf(k1); khi[base + d]      = h; klo[base + d]      = f2bf(k1 - bf2f(h));
    h = f2bf(k2); khi[base + d + 32] = h; klo[base + d + 32] = f2bf(k2 - bf2f(h));
}

// ---------------------------------------------------------------------------
// V: fp32 [bh][n][64] -> bf16-hi transposed [bh][64][VT_STRIDE].
// One block per (key-tile, bh); LDS-tiled transpose, coalesced both sides.
// ---------------------------------------------------------------------------
__global__ __launch_bounds__(256)
void v_transpose(const float* __restrict__ vf, unsigned short* __restrict__ vt)
{
    __shared__ float t[64][65];
    const int tid = threadIdx.x;
    const int kt0 = blockIdx.x * 64;
    const int bh  = blockIdx.y;
    const float* src = vf + (size_t)bh * N_TOK * 64;

#pragma unroll
    for (int p = 0; p < 4; ++p) {
        const int e   = p * 256 + tid;
        const int key = e >> 4;
        const int c4  = (e & 15) << 2;
        const int gk  = kt0 + key;
        float4 v = make_float4(0.f, 0.f, 0.f, 0.f);
        if (gk < N_TOK) v = *(const float4*)(src + (size_t)gk * 64 + c4);
        t[key][c4 + 0] = v.x;
        t[key][c4 + 1] = v.y;
        t[key][c4 + 2] = v.z;
        t[key][c4 + 3] = v.w;
    }
    __syncthreads();

    const int d  = tid >> 2;
    const int kb = (tid & 3) << 4;
    unsigned short buf[16];
#pragma unroll
    for (int j = 0; j < 16; ++j) buf[j] = f2bf(t[kb + j][d]);
    unsigned short* dst = vt + (size_t)bh * 64 * VT_STRIDE + (size_t)d * VT_STRIDE + kt0 + kb;
#pragma unroll
    for (int j = 0; j < 4; ++j)
        *(ushort4*)(dst + j * 4) = *(ushort4*)&buf[j * 4];
}

// ---------------------------------------------------------------------------
// MFMA flash attention v4: same dbuf + 2-phase pipeline as v3 (passed twice),
// re-shaped from 4 waves x 32 q-rows to 8 WAVES x 16 Q-ROWS (512 threads).
// Identical LDS (64KB) but half the per-wave register state (VGPR ~85), so
// __launch_bounds__(512,4) gives 2 blocks/CU x 8 waves = 16 waves/CU (4/SIMD)
// -- double the TLP of v3 to hide the softmax dependency chains.
// Staging is one 512-thread pass (3 global_load_lds per thread per tile).
// grid.x = bh so all q-tiles of one bh land on XCD bh%8 (K/V L2 reuse).
// ---------------------------------------------------------------------------
__global__ __launch_bounds__(512, 4)
void attn_mfma2(const unsigned short* __restrict__ qhi_g, const unsigned short* __restrict__ qlo_g,
                const unsigned short* __restrict__ khi_g, const unsigned short* __restrict__ klo_g,
                const unsigned short* __restrict__ vt_g,
                unsigned short* __restrict__ Ohi, unsigned short* __restrict__ Olo)
{
    __shared__ unsigned short Khl[2][64 * 64];   // K hi  [key][d], chunk-swizzled
    __shared__ unsigned short Kll[2][64 * 64];   // K lo
    __shared__ unsigned short Vtl[2][64 * 64];   // V^T hi [d][key], chunk-swizzled
    __shared__ unsigned short Pl[128 * 64];      // P [q][key], elementwise-swizzled

    const int tid  = threadIdx.x;
    const int wave = tid >> 6;      // 0..7, each owns 16 q-rows
    const int lane = tid & 63;
    const int lm   = lane & 15;
    const int quad = lane >> 4;
    const int bh   = blockIdx.x;
    const int q0   = blockIdx.y * 128;
    const int b    = bh >> 4;
    const int h    = bh & 15;

    const unsigned short* Qh  = qhi_g + (size_t)bh * N_TOK * 64;
    const unsigned short* Ql  = qlo_g + (size_t)bh * N_TOK * 64;
    const unsigned short* Khb = khi_g + (size_t)bh * N_TOK * 64;
    const unsigned short* Klb = klo_g + (size_t)bh * N_TOK * 64;
    const unsigned short* Vtb = vt_g  + (size_t)bh * 64 * VT_STRIDE;

    // Stage one 64-key tile (K hi, K lo, V^T hi): 512 chunks of 16B per slab,
    // one chunk per thread. Source carries the bank-decorrelating XOR swizzle;
    // LDS dest stays wave-uniform base + lane*16 (global_load_lds rule).
#define STAGE(bs, kt0_) do {                                                     \
    const int r_  = tid >> 3;                                                    \
    const int qs_ = tid & 7;                                                     \
    const int sw_ = (qs_ ^ (r_ & 7)) << 3;                                       \
    const int ldsoff_ = wave * 512;                                              \
    const int gk_ = min((kt0_) + r_, N_TOK - 1);                                 \
    __builtin_amdgcn_global_load_lds(                                            \
        (__attribute__((address_space(1))) void*)(Khb + (size_t)gk_ * 64 + sw_), \
        (__attribute__((address_space(3))) void*)&Khl[bs][ldsoff_], 16, 0, 0);   \
    __builtin_amdgcn_global_load_lds(                                            \
        (__attribute__((address_space(1))) void*)(Klb + (size_t)gk_ * 64 + sw_), \
        (__attribute__((address_space(3))) void*)&Kll[bs][ldsoff_], 16, 0, 0);   \
    __builtin_amdgcn_global_load_lds(                                            \
        (__attribute__((address_space(1))) void*)(Vtb + (size_t)r_ * VT_STRIDE + (kt0_) + sw_), \
        (__attribute__((address_space(3))) void*)&Vtl[bs][ldsoff_], 16, 0, 0);   \
} while (0)

    // ---- prologue: start tile-0 staging, then Q loads overlap its latency ----
    STAGE(0, 0);

    bf16x8 qh[2], ql[2];
    {
        int row = q0 + wave * 16 + lm;
        if (row > N_TOK - 1) row = N_TOK - 1;
#pragma unroll
        for (int s = 0; s < 2; ++s) {
            const size_t off = (size_t)row * 64 + s * 32 + quad * 8;
            qh[s] = *(const bf16x8*)&Qh[off];
            ql[s] = *(const bf16x8*)&Ql[off];
        }
    }

    f32x4 o[4];
    float m_i[4], l_i[4];
#pragma unroll
    for (int r = 0; r < 4; ++r) {
        m_i[r] = -FLT_MAX;
        l_i[r] = 0.f;
        o[r] = (f32x4){0.f, 0.f, 0.f, 0.f};
    }

    asm volatile("s_waitcnt vmcnt(0)\n\ts_barrier" ::: "memory");

    for (int kt = 0; kt < 17; ++kt) {
        const int kt0 = kt * 64;
        const int cur = kt & 1;

        // ---- prefetch next tile into the other buffer (stays in flight) ----
        if (kt < 16) STAGE(cur ^ 1, kt0 + 64);

        // ---- QK^T: S[16 q][64 key] per wave, from buf[cur] ----
        f32x4 s_acc[4];
#pragma unroll
        for (int ct = 0; ct < 4; ++ct)
            s_acc[ct] = (f32x4){0.f, 0.f, 0.f, 0.f};

#pragma unroll
        for (int ct = 0; ct < 4; ++ct) {
            const int krow = ct * 16 + lm;
#pragma unroll
            for (int s = 0; s < 2; ++s) {
                const int chunk = ((s * 4 + quad) ^ (krow & 7)) << 3;
                const bf16x8 kbh = *(const bf16x8*)&Khl[cur][krow * 64 + chunk];
                const bf16x8 kbl = *(const bf16x8*)&Kll[cur][krow * 64 + chunk];
                s_acc[ct] = __builtin_amdgcn_mfma_f32_16x16x32_bf16(qh[s], kbh, s_acc[ct], 0, 0, 0);
                s_acc[ct] = __builtin_amdgcn_mfma_f32_16x16x32_bf16(qh[s], kbl, s_acc[ct], 0, 0, 0);
                s_acc[ct] = __builtin_amdgcn_mfma_f32_16x16x32_bf16(ql[s], kbh, s_acc[ct], 0, 0, 0);
            }
        }

        // ---- mask OOB keys (last tile only) ----
        if (kt0 + 64 > N_TOK) {
#pragma unroll
            for (int ct = 0; ct < 4; ++ct) {
                if (kt0 + ct * 16 + lm >= N_TOK) {
#pragma unroll
                    for (int r = 0; r < 4; ++r) s_acc[ct][r] = -FLT_MAX;
                }
            }
        }

        // ---- online softmax + publish P ----
#pragma unroll
        for (int r = 0; r < 4; ++r) {
            float mt = fmaxf(fmaxf(s_acc[0][r], s_acc[1][r]),
                             fmaxf(s_acc[2][r], s_acc[3][r]));
            mt = fmaxf(mt, __shfl_xor(mt, 1));
            mt = fmaxf(mt, __shfl_xor(mt, 2));
            mt = fmaxf(mt, __shfl_xor(mt, 4));
            mt = fmaxf(mt, __shfl_xor(mt, 8));
            const float mnew  = fmaxf(m_i[r], mt);
            const float alpha = __expf(m_i[r] - mnew);
            float pv[4], rs = 0.f;
#pragma unroll
            for (int ct = 0; ct < 4; ++ct) {
                pv[ct] = __expf(s_acc[ct][r] - mnew);
                rs += pv[ct];
            }
            rs += __shfl_xor(rs, 1);
            rs += __shfl_xor(rs, 2);
            rs += __shfl_xor(rs, 4);
            rs += __shfl_xor(rs, 8);
            l_i[r] = l_i[r] * alpha + rs;
            m_i[r] = mnew;
#pragma unroll
            for (int dt = 0; dt < 4; ++dt) o[dt][r] *= alpha;
            const int prow = wave * 16 + quad * 4 + r;
#pragma unroll
            for (int ct = 0; ct < 4; ++ct) {
                const int col = ct * 16 + lm;
                const int idx = prow * 64 + ((((col >> 3) ^ (prow & 7)) << 3) | (col & 7));
                Pl[idx] = f2bf(pv[ct]);
            }
        }

        // ---- PV: o += P @ V^T  (wave-private P; V hi only -> 1 MFMA) ----
#pragma unroll
        for (int ks = 0; ks < 2; ++ks) {
            const int prow = wave * 16 + lm;
            const int chunk = ((ks * 4 + quad) ^ (prow & 7)) << 3;
            const bf16x8 pf = *(const bf16x8*)&Pl[prow * 64 + chunk];
#pragma unroll
            for (int dt = 0; dt < 4; ++dt) {
                const int vrow = dt * 16 + lm;
                const int chunkv = ((ks * 4 + quad) ^ (vrow & 7)) << 3;
                const bf16x8 vh = *(const bf16x8*)&Vtl[cur][vrow * 64 + chunkv];
                o[dt] = __builtin_amdgcn_mfma_f32_16x16x32_bf16(pf, vh, o[dt], 0, 0, 0);
            }
        }

        // ---- single per-tile sync: prefetch landed + all frag reads done ----
        asm volatile("s_waitcnt vmcnt(0)\n\ts_barrier" ::: "memory");
    }
#undef STAGE

    // ---- epilogue: normalize, bf16 hi/lo split, store [B,N,H,D] ----
#pragma unroll
    for (int r = 0; r < 4; ++r) {
        const int gq = q0 + wave * 16 + quad * 4 + r;
        if (gq >= N_TOK) continue;
        const float inv = 1.0f / l_i[r];
        const size_t base = (((size_t)(b * N_TOK + gq)) * H_ + h) * D_;
#pragma unroll
        for (int dt = 0; dt < 4; ++dt) {
            const float val = o[dt][r] * inv;
            const unsigned short hb = f2bf(val);
            Ohi[base + dt * 16 + lm] = hb;
            Olo[base + dt * 16 + lm] = f2bf(val - bf2f(hb));
        }
    }
}

// ---------------------------------------------------------------------------
// ws = EXACTLY 4 fp32 slabs (269,746,176 B — proven budget).
//   slab1: q fp32       -> attn_hi/attn_lo (after rope_convert)
//   slab2: k fp32       -> wp_hi/wp_lo     (after rope_convert)
//   slab3: v fp32       -> qhi/qlo         (after v_transpose)
//   slab4: x_hi/x_lo    -> khi/klo         (after GEMM1)
//   d_out: wq_hi/wq_lo (during GEMM1) -> vthi (35.7MB, until GEMM2 overwrites)
// ---------------------------------------------------------------------------
extern "C" void kernel_launch(void* const* d_in, const int* in_sizes, int n_in,
                              void* d_out, int out_size, void* d_ws, size_t ws_size,
                              hipStream_t stream)
{
    const float* x        = (const float*)d_in[0];
    const float* rope_sin = (const float*)d_in[1];
    const float* rope_cos = (const float*)d_in[2];
    const float* W_qkv    = (const float*)d_in[3];
    const float* b_qkv    = (const float*)d_in[4];
    const float* W_proj   = (const float*)d_in[5];
    const float* b_proj   = (const float*)d_in[6];
    float* out = (float*)d_out;

    float* q_buf = (float*)d_ws;
    float* k_buf = q_buf + HEAD_SLAB;
    float* v_buf = q_buf + 2 * HEAD_SLAB;
    float* slab4 = q_buf + 3 * HEAD_SLAB;

    unsigned short* x_hi = (unsigned short*)slab4;
    unsigned short* x_lo = x_hi + HEAD_SLAB;
    unsigned short* wq_hi = (unsigned short*)d_out;
    unsigned short* wq_lo = wq_hi + (size_t)3 * C_ * C_;

    unsigned short* vthi  = (unsigned short*)d_out;          // after GEMM1
    unsigned short* qhi   = (unsigned short*)v_buf;          // after v_transpose
    unsigned short* qlo   = qhi + HEAD_SLAB;
    unsigned short* khi   = (unsigned short*)slab4;          // after GEMM1
    unsigned short* klo   = khi + HEAD_SLAB;
    unsigned short* attn_hi = (unsigned short*)q_buf;        // after rope_convert
    unsigned short* attn_lo = attn_hi + HEAD_SLAB;
    unsigned short* wp_hi = (unsigned short*)k_buf;          // after rope_convert
    unsigned short* wp_lo = wp_hi + (size_t)C_ * C_;

    // 0) fp32 -> bf16 hi/lo splits for x and W_qkv
    {
        const int n4x = M_ROWS * C_ / 4;
        split_kernel<<<(n4x + 255) / 256, 256, 0, stream>>>(x, x_hi, x_lo, n4x);
        const int n4q = 3 * C_ * C_ / 4;
        split_kernel<<<(n4q + 255) / 256, 256, 0, stream>>>(W_qkv, wq_hi, wq_lo, n4q);
    }
    // 1) QKV projection (MFMA, 256x256 pipelined) -> q/k/v fp32 [B,H,N,D]
    {
        dim3 grid(3 * C_ / 256, (M_ROWS + 255) / 256);
        gemm_mfma8<<<grid, 512, 0, stream>>>(x_hi, x_lo, wq_hi, wq_lo, b_qkv,
                                             q_buf, M_ROWS, 3 * C_, C_, 1);
    }
    // 2a) V -> bf16-hi transposed slab (in d_out; wq splits now dead)
    {
        dim3 grid(17, B_ * H_);
        v_transpose<<<grid, 256, 0, stream>>>(v_buf, vthi);
    }
    // 2b) RoPE + split q,k -> bf16 hi/lo slabs (v fp32 now dead)
    {
        const int total = B_ * H_ * N_TOK * 32;
        rope_convert<<<(total + 255) / 256, 256, 0, stream>>>(
            q_buf, k_buf, rope_sin, rope_cos, qhi, qlo, khi, klo);
    }
    // 3) MFMA flash attention (8-wave) -> attn hi/lo bf16 [B,N,H,D]
    {
        dim3 grid(B_ * H_, (N_TOK + 127) / 128);   // x=bh: XCD locality
        attn_mfma2<<<grid, 512, 0, stream>>>(qhi, qlo, khi, klo, vthi,
                                             attn_hi, attn_lo);
    }
    // 3b) split W_proj into dead k-slab
    {
        const int n4p = C_ * C_ / 4;
        split_kernel<<<(n4p + 255) / 256, 256, 0, stream>>>(W_proj, wp_hi, wp_lo, n4p);
    }
    // 4) Output projection (MFMA, 256x256 pipelined) -> d_out (overwrites vthi)
    {
        dim3 grid(C_ / 256, (M_ROWS + 255) / 256);
        gemm_mfma8<<<grid, 512, 0, stream>>>(attn_hi, attn_lo, wp_hi, wp_lo, b_proj,
                                             out, M_ROWS, C_, C_, 0);
    }
}

// Round 5
// 886.302 us; speedup vs baseline: 1.0686x; 1.0686x over previous
//
#include <hip/hip_runtime.h>
#include <cfloat>
#include <math.h>

#define B_      16
#define N_TOK   1029
#define C_      1024
#define H_      16
#define D_      64
#define PREFIX  5
#define M_ROWS  (B_ * N_TOK)                       // 16464
#define HEAD_SLAB ((size_t)B_ * H_ * N_TOK * D_)   // 16,859,136 floats (= M_ROWS*C_)
#define VT_STRIDE 1088                             // 17*64: padded key dim for V^T slab

typedef __attribute__((ext_vector_type(8))) short bf16x8;
typedef __attribute__((ext_vector_type(4))) float f32x4;

// ---- bf16 helpers (RNE), raw ushort storage ------------------------------
__device__ __forceinline__ unsigned short f2bf(float f) {
    unsigned u = __float_as_uint(f);
    u += 0x7fffu + ((u >> 16) & 1u);          // round-to-nearest-even
    return (unsigned short)(u >> 16);
}
__device__ __forceinline__ float bf2f(unsigned short h) {
    return __uint_as_float(((unsigned)h) << 16);
}

// ---------------------------------------------------------------------------
// Split fp32 array into bf16 hi + bf16 lo (residual). n4 = count/4.
// ---------------------------------------------------------------------------
__global__ __launch_bounds__(256)
void split_kernel(const float* __restrict__ in, unsigned short* __restrict__ hi,
                  unsigned short* __restrict__ lo, int n4)
{
    const int i = blockIdx.x * 256 + threadIdx.x;
    if (i >= n4) return;
    const float4 v = ((const float4*)in)[i];
    ushort4 h, l;
    h.x = f2bf(v.x); l.x = f2bf(v.x - bf2f(h.x));
    h.y = f2bf(v.y); l.y = f2bf(v.y - bf2f(h.y));
    h.z = f2bf(v.z); l.z = f2bf(v.z - bf2f(h.z));
    h.w = f2bf(v.w); l.w = f2bf(v.w - bf2f(h.w));
    ((ushort4*)hi)[i] = h;
    ((ushort4*)lo)[i] = l;
}

// ---------------------------------------------------------------------------
// 3-phase pipelined MFMA GEMM, 256x256 tile, BK=32, 512 threads (8 waves 2Mx4N).
// Main loop UNCHANGED from the round-3/4 passing version. The scatter epilogue
// is now FUSED: bias -> RoPE -> (q: x0.125) -> bf16 hi/lo split, writing
// qhi/qlo/khi/klo and vhi (bf16-hi only) directly. Pairing works because the
// RoPE partner cols (d, d+32) are acc[mi][ni] and acc[mi][ni+2] of the SAME
// thread (d = ni*16+lm, wn*64 == 0 mod 64), and which=rowB>>10 is block-
// uniform (256-col tiles never straddle a 1024 boundary). This deletes the
// separate rope_convert kernel and the fp32 q/k/v round-trip.
// ---------------------------------------------------------------------------
__device__ __forceinline__ bf16x8 frag_ld(const unsigned short* slab, int r, int q) {
    const int L = r >> 1;
    const int s = (q | ((r & 1) << 2)) ^ (L & 7);
    return *(const bf16x8*)(slab + L * 64 + s * 8);
}

#define WAIT_BAR(N) do {                                          \
    asm volatile("s_waitcnt vmcnt(" #N ")" ::: "memory");         \
    __builtin_amdgcn_s_barrier();                                 \
    __builtin_amdgcn_sched_barrier(0);                            \
} while (0)

__global__ __launch_bounds__(512, 2)
void gemm_mfma8(const unsigned short* __restrict__ Ahi, const unsigned short* __restrict__ Alo,
                const unsigned short* __restrict__ Whi, const unsigned short* __restrict__ Wlo,
                const float* __restrict__ bias, float* __restrict__ out,
                int M, int Ncols, int K, int scatter,
                const float* __restrict__ sinv, const float* __restrict__ cosv,
                unsigned short* __restrict__ qhi_o, unsigned short* __restrict__ qlo_o,
                unsigned short* __restrict__ khi_o, unsigned short* __restrict__ klo_o,
                unsigned short* __restrict__ vhi_o)
{
    __shared__ unsigned short lds[2][4][256 * 32];   // 128 KB: [buf][0=Ahi,1=Alo,2=Bhi,3=Blo]

    const int tid  = threadIdx.x;
    const int wave = tid >> 6;
    const int lane = tid & 63;
    const int lm   = lane & 15;
    const int quad = lane >> 4;
    const int bx = blockIdx.x, by = blockIdx.y;
    const int wm = wave >> 2;          // 0..1  (M half)
    const int wn = wave & 3;           // 0..3  (N quarter)
    const int rowA = by * 256;
    const int rowB = bx * 256;

    f32x4 acc[8][4];
#pragma unroll
    for (int mi = 0; mi < 8; ++mi)
#pragma unroll
        for (int ni = 0; ni < 4; ++ni)
            acc[mi][ni] = (f32x4){0.f, 0.f, 0.f, 0.f};

#define STAGE(buf_, slab_, base_, row0_, doClamp_, k0_) do {                          \
    _Pragma("unroll")                                                                 \
    for (int i_ = 0; i_ < 2; ++i_) {                                                  \
        const int c_ = i_ * 512 + tid;                                                \
        const int L_ = c_ >> 3;                                                       \
        const int u_ = (c_ & 7) ^ (L_ & 7);                                           \
        int grow_ = (row0_) + 2 * L_ + (u_ >> 2);                                     \
        if (doClamp_) grow_ = min(grow_, M - 1);                                      \
        const unsigned short* src_ = (base_) + (size_t)grow_ * K + (k0_) + (u_ & 3) * 8; \
        __builtin_amdgcn_global_load_lds(                                             \
            (__attribute__((address_space(1))) void*)src_,                            \
            (__attribute__((address_space(3))) void*)&lds[buf_][slab_][(i_ * 512 + wave * 64) * 8], \
            16, 0, 0);                                                                \
    }                                                                                 \
} while (0)

    // Prologue: tile 0, issue order {Ahi,Bhi} then {Blo} then {Alo}.
    STAGE(0, 0, Ahi, rowA, true,  0);
    STAGE(0, 2, Whi, rowB, false, 0);
    STAGE(0, 3, Wlo, rowB, false, 0);
    STAGE(0, 1, Alo, rowA, true,  0);

    const int NT = K >> 5;             // K-tiles of BK=32
    for (int t = 0; t < NT; ++t) {
        const int cur = t & 1, nxt = cur ^ 1;
        const int tn = (t + 1 == NT) ? 0 : t + 1;   // wrap-stage: uniform counts
        const int k1 = tn << 5;

        // ---------- P0: acc += Ahi*Bhi ----------
        WAIT_BAR(4);
        STAGE(nxt, 0, Ahi, rowA, true,  k1);
        STAGE(nxt, 2, Whi, rowB, false, k1);
        bf16x8 b[4], a[8];
#pragma unroll
        for (int ni = 0; ni < 4; ++ni)
            b[ni] = frag_ld(&lds[cur][2][0], wn * 64 + ni * 16 + lm, quad);
#pragma unroll
        for (int mi = 0; mi < 8; ++mi)
            a[mi] = frag_ld(&lds[cur][0][0], wm * 128 + mi * 16 + lm, quad);
        __builtin_amdgcn_s_setprio(1);
#pragma unroll
        for (int mi = 0; mi < 8; ++mi)
#pragma unroll
            for (int ni = 0; ni < 4; ++ni)
                acc[mi][ni] = __builtin_amdgcn_mfma_f32_16x16x32_bf16(a[mi], b[ni], acc[mi][ni], 0, 0, 0);
        __builtin_amdgcn_s_setprio(0);

        // ---------- P1: acc += Ahi*Blo ----------
        WAIT_BAR(6);
        STAGE(nxt, 3, Wlo, rowB, false, k1);
        __builtin_amdgcn_s_setprio(1);
#pragma unroll
        for (int ni = 0; ni < 4; ++ni) {
            const bf16x8 bl = frag_ld(&lds[cur][3][0], wn * 64 + ni * 16 + lm, quad);
#pragma unroll
            for (int mi = 0; mi < 8; ++mi)
                acc[mi][ni] = __builtin_amdgcn_mfma_f32_16x16x32_bf16(a[mi], bl, acc[mi][ni], 0, 0, 0);
        }
        __builtin_amdgcn_s_setprio(0);

        // ---------- P2: acc += Alo*Bhi ----------
        WAIT_BAR(6);
        STAGE(nxt, 1, Alo, rowA, true, k1);
        __builtin_amdgcn_s_setprio(1);
#pragma unroll
        for (int mi = 0; mi < 8; ++mi) {
            const bf16x8 al = frag_ld(&lds[cur][1][0], wm * 128 + mi * 16 + lm, quad);
#pragma unroll
            for (int ni = 0; ni < 4; ++ni)
                acc[mi][ni] = __builtin_amdgcn_mfma_f32_16x16x32_bf16(al, b[ni], acc[mi][ni], 0, 0, 0);
        }
        __builtin_amdgcn_s_setprio(0);
    }
#undef STAGE
    asm volatile("s_waitcnt vmcnt(0)" ::: "memory");

    // ---- epilogue ----
    if (!scatter) {
        // plain: bias + fp32 store
#pragma unroll
        for (int mi = 0; mi < 8; ++mi) {
#pragma unroll
            for (int rr = 0; rr < 4; ++rr) {
                const int gm = rowA + wm * 128 + mi * 16 + quad * 4 + rr;
                if (gm >= M) continue;
#pragma unroll
                for (int ni = 0; ni < 4; ++ni) {
                    const int gn = rowB + wn * 64 + ni * 16 + lm;
                    out[(size_t)gm * Ncols + gn] = acc[mi][ni][rr] + bias[gn];
                }
            }
        }
    } else {
        // fused QKV epilogue: bias -> RoPE -> (q: x0.125) -> bf16 hi/lo split
        const int which = rowB >> 10;          // block-uniform: 0=q, 1=k, 2=v
#pragma unroll
        for (int mi = 0; mi < 8; ++mi) {
#pragma unroll
            for (int rr = 0; rr < 4; ++rr) {
                const int gm = rowA + wm * 128 + mi * 16 + quad * 4 + rr;
                if (gm >= M) continue;
                const int b_  = gm / N_TOK;
                const int tok = gm - b_ * N_TOK;
                if (which == 2) {
                    // v: bf16 hi only, [bh][tok][d]
#pragma unroll
                    for (int ni = 0; ni < 4; ++ni) {
                        const int gn = rowB + wn * 64 + ni * 16 + lm;
                        const int h  = (gn >> 6) & 15;
                        const int d  = gn & 63;
                        const float val = acc[mi][ni][rr] + bias[gn];
                        vhi_o[(((size_t)(b_ * H_ + h)) * N_TOK + tok) * 64 + d] = f2bf(val);
                    }
                } else {
                    unsigned short* hi_ = (which == 0) ? qhi_o : khi_o;
                    unsigned short* lo_ = (which == 0) ? qlo_o : klo_o;
                    const float scl = (which == 0) ? 0.125f : 1.0f;
#pragma unroll
                    for (int pr = 0; pr < 2; ++pr) {   // RoPE pairs (ni=pr, ni=pr+2)
                        const int gn1 = rowB + wn * 64 + pr * 16 + lm;
                        const int h   = (gn1 >> 6) & 15;
                        const int d1  = gn1 & 63;      // in [0,32)
                        float v1 = acc[mi][pr][rr]     + bias[gn1];
                        float v2 = acc[mi][pr + 2][rr] + bias[gn1 + 32];
                        if (tok >= PREFIX) {
                            const int r0 = (tok - PREFIX) * 64 + d1;
                            const float c1 = cosv[r0],      s1 = sinv[r0];
                            const float c2 = cosv[r0 + 32], s2 = sinv[r0 + 32];
                            const float n1 = v1 * c1 - v2 * s1;
                            const float n2 = v2 * c2 + v1 * s2;
                            v1 = n1; v2 = n2;
                        }
                        v1 *= scl; v2 *= scl;
                        const size_t base = (((size_t)(b_ * H_ + h)) * N_TOK + tok) * 64 + d1;
                        unsigned short hb;
                        hb = f2bf(v1); hi_[base]      = hb; lo_[base]      = f2bf(v1 - bf2f(hb));
                        hb = f2bf(v2); hi_[base + 32] = hb; lo_[base + 32] = f2bf(v2 - bf2f(hb));
                    }
                }
            }
        }
    }
}
#undef WAIT_BAR

// ---------------------------------------------------------------------------
// V: bf16-hi [bh][n][64] -> transposed [bh][64][VT_STRIDE] (pure shuffle,
// values already bf16). LDS-tiled, coalesced both sides.
// ---------------------------------------------------------------------------
__global__ __launch_bounds__(256)
void v_transpose(const unsigned short* __restrict__ vf, unsigned short* __restrict__ vt)
{
    __shared__ unsigned short t[64][72];
    const int tid = threadIdx.x;
    const int kt0 = blockIdx.x * 64;
    const int bh  = blockIdx.y;
    const unsigned short* src = vf + (size_t)bh * N_TOK * 64;

#pragma unroll
    for (int p = 0; p < 2; ++p) {
        const int e   = p * 256 + tid;       // 512 chunks of 8 ushorts
        const int key = e >> 3;
        const int c8  = (e & 7) << 3;
        const int gk  = kt0 + key;
        ushort4 a = make_ushort4(0, 0, 0, 0), b = a;
        if (gk < N_TOK) {
            a = *(const ushort4*)(src + (size_t)gk * 64 + c8);
            b = *(const ushort4*)(src + (size_t)gk * 64 + c8 + 4);
        }
        *(ushort4*)&t[key][c8]     = a;
        *(ushort4*)&t[key][c8 + 4] = b;
    }
    __syncthreads();

    const int d  = tid >> 2;
    const int kb = (tid & 3) << 4;
    unsigned short buf[16];
#pragma unroll
    for (int j = 0; j < 16; ++j) buf[j] = t[kb + j][d];
    unsigned short* dst = vt + (size_t)bh * 64 * VT_STRIDE + (size_t)d * VT_STRIDE + kt0 + kb;
#pragma unroll
    for (int j = 0; j < 4; ++j)
        *(ushort4*)(dst + j * 4) = *(ushort4*)&buf[j * 4];
}

// ---------------------------------------------------------------------------
// MFMA flash attention v4 (UNCHANGED from round-4 passing version).
// 8 waves x 16 q-rows, dbuf K/V staging, per-tile vmcnt(0)+barrier pipeline.
// ---------------------------------------------------------------------------
__global__ __launch_bounds__(512, 4)
void attn_mfma2(const unsigned short* __restrict__ qhi_g, const unsigned short* __restrict__ qlo_g,
                const unsigned short* __restrict__ khi_g, const unsigned short* __restrict__ klo_g,
                const unsigned short* __restrict__ vt_g,
                unsigned short* __restrict__ Ohi, unsigned short* __restrict__ Olo)
{
    __shared__ unsigned short Khl[2][64 * 64];   // K hi  [key][d], chunk-swizzled
    __shared__ unsigned short Kll[2][64 * 64];   // K lo
    __shared__ unsigned short Vtl[2][64 * 64];   // V^T hi [d][key], chunk-swizzled
    __shared__ unsigned short Pl[128 * 64];      // P [q][key], elementwise-swizzled

    const int tid  = threadIdx.x;
    const int wave = tid >> 6;      // 0..7, each owns 16 q-rows
    const int lane = tid & 63;
    const int lm   = lane & 15;
    const int quad = lane >> 4;
    const int bh   = blockIdx.x;
    const int q0   = blockIdx.y * 128;
    const int b    = bh >> 4;
    const int h    = bh & 15;

    const unsigned short* Qh  = qhi_g + (size_t)bh * N_TOK * 64;
    const unsigned short* Ql  = qlo_g + (size_t)bh * N_TOK * 64;
    const unsigned short* Khb = khi_g + (size_t)bh * N_TOK * 64;
    const unsigned short* Klb = klo_g + (size_t)bh * N_TOK * 64;
    const unsigned short* Vtb = vt_g  + (size_t)bh * 64 * VT_STRIDE;

#define STAGE(bs, kt0_) do {                                                     \
    const int r_  = tid >> 3;                                                    \
    const int qs_ = tid & 7;                                                     \
    const int sw_ = (qs_ ^ (r_ & 7)) << 3;                                       \
    const int ldsoff_ = wave * 512;                                              \
    const int gk_ = min((kt0_) + r_, N_TOK - 1);                                 \
    __builtin_amdgcn_global_load_lds(                                            \
        (__attribute__((address_space(1))) void*)(Khb + (size_t)gk_ * 64 + sw_), \
        (__attribute__((address_space(3))) void*)&Khl[bs][ldsoff_], 16, 0, 0);   \
    __builtin_amdgcn_global_load_lds(                                            \
        (__attribute__((address_space(1))) void*)(Klb + (size_t)gk_ * 64 + sw_), \
        (__attribute__((address_space(3))) void*)&Kll[bs][ldsoff_], 16, 0, 0);   \
    __builtin_amdgcn_global_load_lds(                                            \
        (__attribute__((address_space(1))) void*)(Vtb + (size_t)r_ * VT_STRIDE + (kt0_) + sw_), \
        (__attribute__((address_space(3))) void*)&Vtl[bs][ldsoff_], 16, 0, 0);   \
} while (0)

    // ---- prologue: start tile-0 staging, then Q loads overlap its latency ----
    STAGE(0, 0);

    bf16x8 qh[2], ql[2];
    {
        int row = q0 + wave * 16 + lm;
        if (row > N_TOK - 1) row = N_TOK - 1;
#pragma unroll
        for (int s = 0; s < 2; ++s) {
            const size_t off = (size_t)row * 64 + s * 32 + quad * 8;
            qh[s] = *(const bf16x8*)&Qh[off];
            ql[s] = *(const bf16x8*)&Ql[off];
        }
    }

    f32x4 o[4];
    float m_i[4], l_i[4];
#pragma unroll
    for (int r = 0; r < 4; ++r) {
        m_i[r] = -FLT_MAX;
        l_i[r] = 0.f;
        o[r] = (f32x4){0.f, 0.f, 0.f, 0.f};
    }

    asm volatile("s_waitcnt vmcnt(0)\n\ts_barrier" ::: "memory");

    for (int kt = 0; kt < 17; ++kt) {
        const int kt0 = kt * 64;
        const int cur = kt & 1;

        // ---- prefetch next tile into the other buffer (stays in flight) ----
        if (kt < 16) STAGE(cur ^ 1, kt0 + 64);

        // ---- QK^T: S[16 q][64 key] per wave, from buf[cur] ----
        f32x4 s_acc[4];
#pragma unroll
        for (int ct = 0; ct < 4; ++ct)
            s_acc[ct] = (f32x4){0.f, 0.f, 0.f, 0.f};

#pragma unroll
        for (int ct = 0; ct < 4; ++ct) {
            const int krow = ct * 16 + lm;
#pragma unroll
            for (int s = 0; s < 2; ++s) {
                const int chunk = ((s * 4 + quad) ^ (krow & 7)) << 3;
                const bf16x8 kbh = *(const bf16x8*)&Khl[cur][krow * 64 + chunk];
                const bf16x8 kbl = *(const bf16x8*)&Kll[cur][krow * 64 + chunk];
                s_acc[ct] = __builtin_amdgcn_mfma_f32_16x16x32_bf16(qh[s], kbh, s_acc[ct], 0, 0, 0);
                s_acc[ct] = __builtin_amdgcn_mfma_f32_16x16x32_bf16(qh[s], kbl, s_acc[ct], 0, 0, 0);
                s_acc[ct] = __builtin_amdgcn_mfma_f32_16x16x32_bf16(ql[s], kbh, s_acc[ct], 0, 0, 0);
            }
        }

        // ---- mask OOB keys (last tile only) ----
        if (kt0 + 64 > N_TOK) {
#pragma unroll
            for (int ct = 0; ct < 4; ++ct) {
                if (kt0 + ct * 16 + lm >= N_TOK) {
#pragma unroll
                    for (int r = 0; r < 4; ++r) s_acc[ct][r] = -FLT_MAX;
                }
            }
        }

        // ---- online softmax + publish P ----
#pragma unroll
        for (int r = 0; r < 4; ++r) {
            float mt = fmaxf(fmaxf(s_acc[0][r], s_acc[1][r]),
                             fmaxf(s_acc[2][r], s_acc[3][r]));
            mt = fmaxf(mt, __shfl_xor(mt, 1));
            mt = fmaxf(mt, __shfl_xor(mt, 2));
            mt = fmaxf(mt, __shfl_xor(mt, 4));
            mt = fmaxf(mt, __shfl_xor(mt, 8));
            const float mnew  = fmaxf(m_i[r], mt);
            const float alpha = __expf(m_i[r] - mnew);
            float pv[4], rs = 0.f;
#pragma unroll
            for (int ct = 0; ct < 4; ++ct) {
                pv[ct] = __expf(s_acc[ct][r] - mnew);
                rs += pv[ct];
            }
            rs += __shfl_xor(rs, 1);
            rs += __shfl_xor(rs, 2);
            rs += __shfl_xor(rs, 4);
            rs += __shfl_xor(rs, 8);
            l_i[r] = l_i[r] * alpha + rs;
            m_i[r] = mnew;
#pragma unroll
            for (int dt = 0; dt < 4; ++dt) o[dt][r] *= alpha;
            const int prow = wave * 16 + quad * 4 + r;
#pragma unroll
            for (int ct = 0; ct < 4; ++ct) {
                const int col = ct * 16 + lm;
                const int idx = prow * 64 + ((((col >> 3) ^ (prow & 7)) << 3) | (col & 7));
                Pl[idx] = f2bf(pv[ct]);
            }
        }

        // ---- PV: o += P @ V^T  (wave-private P; V hi only -> 1 MFMA) ----
#pragma unroll
        for (int ks = 0; ks < 2; ++ks) {
            const int prow = wave * 16 + lm;
            const int chunk = ((ks * 4 + quad) ^ (prow & 7)) << 3;
            const bf16x8 pf = *(const bf16x8*)&Pl[prow * 64 + chunk];
#pragma unroll
            for (int dt = 0; dt < 4; ++dt) {
                const int vrow = dt * 16 + lm;
                const int chunkv = ((ks * 4 + quad) ^ (vrow & 7)) << 3;
                const bf16x8 vh = *(const bf16x8*)&Vtl[cur][vrow * 64 + chunkv];
                o[dt] = __builtin_amdgcn_mfma_f32_16x16x32_bf16(pf, vh, o[dt], 0, 0, 0);
            }
        }

        // ---- single per-tile sync: prefetch landed + all frag reads done ----
        asm volatile("s_waitcnt vmcnt(0)\n\ts_barrier" ::: "memory");
    }
#undef STAGE

    // ---- epilogue: normalize, bf16 hi/lo split, store [B,N,H,D] ----
#pragma unroll
    for (int r = 0; r < 4; ++r) {
        const int gq = q0 + wave * 16 + quad * 4 + r;
        if (gq >= N_TOK) continue;
        const float inv = 1.0f / l_i[r];
        const size_t base = (((size_t)(b * N_TOK + gq)) * H_ + h) * D_;
#pragma unroll
        for (int dt = 0; dt < 4; ++dt) {
            const float val = o[dt][r] * inv;
            const unsigned short hb = f2bf(val);
            Ohi[base + dt * 16 + lm] = hb;
            Olo[base + dt * 16 + lm] = f2bf(val - bf2f(hb));
        }
    }
}

// ---------------------------------------------------------------------------
// ws = EXACTLY 4 fp32 slabs (269,746,176 B — proven budget). New map:
//   slab1: qhi/qlo   (GEMM1 fused out)  — dead after attn
//   slab2: khi/klo   (GEMM1 fused out)  — dead after attn -> wp_hi/wp_lo
//   slab3: vhi bf16  (GEMM1 fused out)  — dead after v_transpose
//   slab4: x_hi/x_lo (pre-GEMM1)        — dead after GEMM1 -> attn_hi/attn_lo
//   d_out: wq_hi/wq_lo -> vthi (after GEMM1) -> final out (GEMM2)
// rope_convert kernel is GONE (fused into GEMM1 epilogue).
// ---------------------------------------------------------------------------
extern "C" void kernel_launch(void* const* d_in, const int* in_sizes, int n_in,
                              void* d_out, int out_size, void* d_ws, size_t ws_size,
                              hipStream_t stream)
{
    const float* x        = (const float*)d_in[0];
    const float* rope_sin = (const float*)d_in[1];
    const float* rope_cos = (const float*)d_in[2];
    const float* W_qkv    = (const float*)d_in[3];
    const float* b_qkv    = (const float*)d_in[4];
    const float* W_proj   = (const float*)d_in[5];
    const float* b_proj   = (const float*)d_in[6];
    float* out = (float*)d_out;

    float* slab1 = (float*)d_ws;
    float* slab2 = slab1 + HEAD_SLAB;
    float* slab3 = slab1 + 2 * HEAD_SLAB;
    float* slab4 = slab1 + 3 * HEAD_SLAB;

    unsigned short* x_hi = (unsigned short*)slab4;
    unsigned short* x_lo = x_hi + HEAD_SLAB;
    unsigned short* wq_hi = (unsigned short*)d_out;
    unsigned short* wq_lo = wq_hi + (size_t)3 * C_ * C_;

    unsigned short* qhi = (unsigned short*)slab1;
    unsigned short* qlo = qhi + HEAD_SLAB;
    unsigned short* khi = (unsigned short*)slab2;
    unsigned short* klo = khi + HEAD_SLAB;
    unsigned short* vhi = (unsigned short*)slab3;

    unsigned short* vthi = (unsigned short*)d_out;           // after GEMM1
    unsigned short* attn_hi = (unsigned short*)slab4;        // after GEMM1 (x dead)
    unsigned short* attn_lo = attn_hi + HEAD_SLAB;
    unsigned short* wp_hi = (unsigned short*)slab2;          // after attn (k dead)
    unsigned short* wp_lo = wp_hi + (size_t)C_ * C_;

    // 0) fp32 -> bf16 hi/lo splits for x and W_qkv
    {
        const int n4x = M_ROWS * C_ / 4;
        split_kernel<<<(n4x + 255) / 256, 256, 0, stream>>>(x, x_hi, x_lo, n4x);
        const int n4q = 3 * C_ * C_ / 4;
        split_kernel<<<(n4q + 255) / 256, 256, 0, stream>>>(W_qkv, wq_hi, wq_lo, n4q);
    }
    // 1) QKV projection + fused bias/RoPE/split -> qhi/qlo, khi/klo, vhi
    {
        dim3 grid(3 * C_ / 256, (M_ROWS + 255) / 256);
        gemm_mfma8<<<grid, 512, 0, stream>>>(x_hi, x_lo, wq_hi, wq_lo, b_qkv,
                                             out, M_ROWS, 3 * C_, C_, 1,
                                             rope_sin, rope_cos,
                                             qhi, qlo, khi, klo, vhi);
    }
    // 2) V bf16-hi -> transposed slab (in d_out; wq splits now dead)
    {
        dim3 grid(17, B_ * H_);
        v_transpose<<<grid, 256, 0, stream>>>(vhi, vthi);
    }
    // 3) MFMA flash attention (8-wave) -> attn hi/lo bf16 [B,N,H,D] in slab4
    {
        dim3 grid(B_ * H_, (N_TOK + 127) / 128);   // x=bh: XCD locality
        attn_mfma2<<<grid, 512, 0, stream>>>(qhi, qlo, khi, klo, vthi,
                                             attn_hi, attn_lo);
    }
    // 3b) split W_proj into dead k-slab
    {
        const int n4p = C_ * C_ / 4;
        split_kernel<<<(n4p + 255) / 256, 256, 0, stream>>>(W_proj, wp_hi, wp_lo, n4p);
    }
    // 4) Output projection (MFMA, 256x256 pipelined) -> d_out (overwrites vthi)
    {
        dim3 grid(C_ / 256, (M_ROWS + 255) / 256);
        gemm_mfma8<<<grid, 512, 0, stream>>>(attn_hi, attn_lo, wp_hi, wp_lo, b_proj,
                                             out, M_ROWS, C_, C_, 0,
                                             nullptr, nullptr,
                                             nullptr, nullptr, nullptr, nullptr, nullptr);
    }
}

// Round 7
// 835.713 us; speedup vs baseline: 1.1333x; 1.0605x over previous
//
#include <hip/hip_runtime.h>
#include <cfloat>
#include <math.h>

#define B_      16
#define N_TOK   1029
#define C_      1024
#define H_      16
#define D_      64
#define PREFIX  5
#define M_ROWS  (B_ * N_TOK)                       // 16464
#define HEAD_SLAB ((size_t)B_ * H_ * N_TOK * D_)   // 16,859,136 floats (= M_ROWS*C_)
#define VT_STRIDE 1088                             // 17*64: padded key dim for V^T slab
#define QSCALE  0.18033688011112042f               // 0.125 * log2(e): exp2-domain softmax

typedef __attribute__((ext_vector_type(8))) short bf16x8;
typedef __attribute__((ext_vector_type(4))) float f32x4;

// ---- bf16 helpers (RNE), raw ushort storage ------------------------------
__device__ __forceinline__ unsigned short f2bf(float f) {
    unsigned u = __float_as_uint(f);
    u += 0x7fffu + ((u >> 16) & 1u);          // round-to-nearest-even
    return (unsigned short)(u >> 16);
}
__device__ __forceinline__ float bf2f(unsigned short h) {
    return __uint_as_float(((unsigned)h) << 16);
}
// base-2 exp -> bare v_exp_f32 (no log2e multiply)
__device__ __forceinline__ float fexp2(float x) {
#if __has_builtin(__builtin_amdgcn_exp2f)
    return __builtin_amdgcn_exp2f(x);
#else
    return exp2f(x);
#endif
}

// ---------------------------------------------------------------------------
// Split fp32 array into bf16 hi + bf16 lo (residual). n4 = count/4.
// ---------------------------------------------------------------------------
__global__ __launch_bounds__(256)
void split_kernel(const float* __restrict__ in, unsigned short* __restrict__ hi,
                  unsigned short* __restrict__ lo, int n4)
{
    const int i = blockIdx.x * 256 + threadIdx.x;
    if (i >= n4) return;
    const float4 v = ((const float4*)in)[i];
    ushort4 h, l;
    h.x = f2bf(v.x); l.x = f2bf(v.x - bf2f(h.x));
    h.y = f2bf(v.y); l.y = f2bf(v.y - bf2f(h.y));
    h.z = f2bf(v.z); l.z = f2bf(v.z - bf2f(h.z));
    h.w = f2bf(v.w); l.w = f2bf(v.w - bf2f(h.w));
    ((ushort4*)hi)[i] = h;
    ((ushort4*)lo)[i] = l;
}

// ---------------------------------------------------------------------------
// 3-phase pipelined MFMA GEMM, 256x256 tile, BK=32, 512 threads (8 waves 2Mx4N).
// Main loop UNCHANGED from the round-3/4/5 passing version. Fused scatter
// epilogue: bias -> RoPE -> (q: xQSCALE) -> bf16 hi/lo split.
// ---------------------------------------------------------------------------
__device__ __forceinline__ bf16x8 frag_ld(const unsigned short* slab, int r, int q) {
    const int L = r >> 1;
    const int s = (q | ((r & 1) << 2)) ^ (L & 7);
    return *(const bf16x8*)(slab + L * 64 + s * 8);
}

#define WAIT_BAR(N) do {                                          \
    asm volatile("s_waitcnt vmcnt(" #N ")" ::: "memory");         \
    __builtin_amdgcn_s_barrier();                                 \
    __builtin_amdgcn_sched_barrier(0);                            \
} while (0)

__global__ __launch_bounds__(512, 2)
void gemm_mfma8(const unsigned short* __restrict__ Ahi, const unsigned short* __restrict__ Alo,
                const unsigned short* __restrict__ Whi, const unsigned short* __restrict__ Wlo,
                const float* __restrict__ bias, float* __restrict__ out,
                int M, int Ncols, int K, int scatter,
                const float* __restrict__ sinv, const float* __restrict__ cosv,
                unsigned short* __restrict__ qhi_o, unsigned short* __restrict__ qlo_o,
                unsigned short* __restrict__ khi_o, unsigned short* __restrict__ klo_o,
                unsigned short* __restrict__ vhi_o)
{
    __shared__ unsigned short lds[2][4][256 * 32];   // 128 KB: [buf][0=Ahi,1=Alo,2=Bhi,3=Blo]

    const int tid  = threadIdx.x;
    const int wave = tid >> 6;
    const int lane = tid & 63;
    const int lm   = lane & 15;
    const int quad = lane >> 4;
    const int bx = blockIdx.x, by = blockIdx.y;
    const int wm = wave >> 2;          // 0..1  (M half)
    const int wn = wave & 3;           // 0..3  (N quarter)
    const int rowA = by * 256;
    const int rowB = bx * 256;

    f32x4 acc[8][4];
#pragma unroll
    for (int mi = 0; mi < 8; ++mi)
#pragma unroll
        for (int ni = 0; ni < 4; ++ni)
            acc[mi][ni] = (f32x4){0.f, 0.f, 0.f, 0.f};

#define STAGE(buf_, slab_, base_, row0_, doClamp_, k0_) do {                          \
    _Pragma("unroll")                                                                 \
    for (int i_ = 0; i_ < 2; ++i_) {                                                  \
        const int c_ = i_ * 512 + tid;                                                \
        const int L_ = c_ >> 3;                                                       \
        const int u_ = (c_ & 7) ^ (L_ & 7);                                           \
        int grow_ = (row0_) + 2 * L_ + (u_ >> 2);                                     \
        if (doClamp_) grow_ = min(grow_, M - 1);                                      \
        const unsigned short* src_ = (base_) + (size_t)grow_ * K + (k0_) + (u_ & 3) * 8; \
        __builtin_amdgcn_global_load_lds(                                             \
            (__attribute__((address_space(1))) void*)src_,                            \
            (__attribute__((address_space(3))) void*)&lds[buf_][slab_][(i_ * 512 + wave * 64) * 8], \
            16, 0, 0);                                                                \
    }                                                                                 \
} while (0)

    // Prologue: tile 0, issue order {Ahi,Bhi} then {Blo} then {Alo}.
    STAGE(0, 0, Ahi, rowA, true,  0);
    STAGE(0, 2, Whi, rowB, false, 0);
    STAGE(0, 3, Wlo, rowB, false, 0);
    STAGE(0, 1, Alo, rowA, true,  0);

    const int NT = K >> 5;             // K-tiles of BK=32
    for (int t = 0; t < NT; ++t) {
        const int cur = t & 1, nxt = cur ^ 1;
        const int tn = (t + 1 == NT) ? 0 : t + 1;   // wrap-stage: uniform counts
        const int k1 = tn << 5;

        // ---------- P0: acc += Ahi*Bhi ----------
        WAIT_BAR(4);
        STAGE(nxt, 0, Ahi, rowA, true,  k1);
        STAGE(nxt, 2, Whi, rowB, false, k1);
        bf16x8 b[4], a[8];
#pragma unroll
        for (int ni = 0; ni < 4; ++ni)
            b[ni] = frag_ld(&lds[cur][2][0], wn * 64 + ni * 16 + lm, quad);
#pragma unroll
        for (int mi = 0; mi < 8; ++mi)
            a[mi] = frag_ld(&lds[cur][0][0], wm * 128 + mi * 16 + lm, quad);
        __builtin_amdgcn_s_setprio(1);
#pragma unroll
        for (int mi = 0; mi < 8; ++mi)
#pragma unroll
            for (int ni = 0; ni < 4; ++ni)
                acc[mi][ni] = __builtin_amdgcn_mfma_f32_16x16x32_bf16(a[mi], b[ni], acc[mi][ni], 0, 0, 0);
        __builtin_amdgcn_s_setprio(0);

        // ---------- P1: acc += Ahi*Blo ----------
        WAIT_BAR(6);
        STAGE(nxt, 3, Wlo, rowB, false, k1);
        __builtin_amdgcn_s_setprio(1);
#pragma unroll
        for (int ni = 0; ni < 4; ++ni) {
            const bf16x8 bl = frag_ld(&lds[cur][3][0], wn * 64 + ni * 16 + lm, quad);
#pragma unroll
            for (int mi = 0; mi < 8; ++mi)
                acc[mi][ni] = __builtin_amdgcn_mfma_f32_16x16x32_bf16(a[mi], bl, acc[mi][ni], 0, 0, 0);
        }
        __builtin_amdgcn_s_setprio(0);

        // ---------- P2: acc += Alo*Bhi ----------
        WAIT_BAR(6);
        STAGE(nxt, 1, Alo, rowA, true, k1);
        __builtin_amdgcn_s_setprio(1);
#pragma unroll
        for (int mi = 0; mi < 8; ++mi) {
            const bf16x8 al = frag_ld(&lds[cur][1][0], wm * 128 + mi * 16 + lm, quad);
#pragma unroll
            for (int ni = 0; ni < 4; ++ni)
                acc[mi][ni] = __builtin_amdgcn_mfma_f32_16x16x32_bf16(al, b[ni], acc[mi][ni], 0, 0, 0);
        }
        __builtin_amdgcn_s_setprio(0);
    }
#undef STAGE
    asm volatile("s_waitcnt vmcnt(0)" ::: "memory");

    // ---- epilogue ----
    if (!scatter) {
        // plain: bias + fp32 store
#pragma unroll
        for (int mi = 0; mi < 8; ++mi) {
#pragma unroll
            for (int rr = 0; rr < 4; ++rr) {
                const int gm = rowA + wm * 128 + mi * 16 + quad * 4 + rr;
                if (gm >= M) continue;
#pragma unroll
                for (int ni = 0; ni < 4; ++ni) {
                    const int gn = rowB + wn * 64 + ni * 16 + lm;
                    out[(size_t)gm * Ncols + gn] = acc[mi][ni][rr] + bias[gn];
                }
            }
        }
    } else {
        // fused QKV epilogue: bias -> RoPE -> (q: xQSCALE) -> bf16 hi/lo split
        const int which = rowB >> 10;          // block-uniform: 0=q, 1=k, 2=v
#pragma unroll
        for (int mi = 0; mi < 8; ++mi) {
#pragma unroll
            for (int rr = 0; rr < 4; ++rr) {
                const int gm = rowA + wm * 128 + mi * 16 + quad * 4 + rr;
                if (gm >= M) continue;
                const int b_  = gm / N_TOK;
                const int tok = gm - b_ * N_TOK;
                if (which == 2) {
                    // v: bf16 hi only, [bh][tok][d]
#pragma unroll
                    for (int ni = 0; ni < 4; ++ni) {
                        const int gn = rowB + wn * 64 + ni * 16 + lm;
                        const int h  = (gn >> 6) & 15;
                        const int d  = gn & 63;
                        const float val = acc[mi][ni][rr] + bias[gn];
                        vhi_o[(((size_t)(b_ * H_ + h)) * N_TOK + tok) * 64 + d] = f2bf(val);
                    }
                } else {
                    unsigned short* hi_ = (which == 0) ? qhi_o : khi_o;
                    unsigned short* lo_ = (which == 0) ? qlo_o : klo_o;
                    const float scl = (which == 0) ? QSCALE : 1.0f;
#pragma unroll
                    for (int pr = 0; pr < 2; ++pr) {   // RoPE pairs (ni=pr, ni=pr+2)
                        const int gn1 = rowB + wn * 64 + pr * 16 + lm;
                        const int h   = (gn1 >> 6) & 15;
                        const int d1  = gn1 & 63;      // in [0,32)
                        float v1 = acc[mi][pr][rr]     + bias[gn1];
                        float v2 = acc[mi][pr + 2][rr] + bias[gn1 + 32];
                        if (tok >= PREFIX) {
                            const int r0 = (tok - PREFIX) * 64 + d1;
                            const float c1 = cosv[r0],      s1 = sinv[r0];
                            const float c2 = cosv[r0 + 32], s2 = sinv[r0 + 32];
                            const float n1 = v1 * c1 - v2 * s1;
                            const float n2 = v2 * c2 + v1 * s2;
                            v1 = n1; v2 = n2;
                        }
                        v1 *= scl; v2 *= scl;
                        const size_t base = (((size_t)(b_ * H_ + h)) * N_TOK + tok) * 64 + d1;
                        unsigned short hb;
                        hb = f2bf(v1); hi_[base]      = hb; lo_[base]      = f2bf(v1 - bf2f(hb));
                        hb = f2bf(v2); hi_[base + 32] = hb; lo_[base + 32] = f2bf(v2 - bf2f(hb));
                    }
                }
            }
        }
    }
}
#undef WAIT_BAR

// ---------------------------------------------------------------------------
// V: bf16-hi [bh][n][64] -> transposed [bh][64][VT_STRIDE] (pure shuffle,
// values already bf16). LDS-tiled, coalesced both sides.
// ---------------------------------------------------------------------------
__global__ __launch_bounds__(256)
void v_transpose(const unsigned short* __restrict__ vf, unsigned short* __restrict__ vt)
{
    __shared__ unsigned short t[64][72];
    const int tid = threadIdx.x;
    const int kt0 = blockIdx.x * 64;
    const int bh  = blockIdx.y;
    const unsigned short* src = vf + (size_t)bh * N_TOK * 64;

#pragma unroll
    for (int p = 0; p < 2; ++p) {
        const int e   = p * 256 + tid;       // 512 chunks of 8 ushorts
        const int key = e >> 3;
        const int c8  = (e & 7) << 3;
        const int gk  = kt0 + key;
        ushort4 a = make_ushort4(0, 0, 0, 0), b = a;
        if (gk < N_TOK) {
            a = *(const ushort4*)(src + (size_t)gk * 64 + c8);
            b = *(const ushort4*)(src + (size_t)gk * 64 + c8 + 4);
        }
        *(ushort4*)&t[key][c8]     = a;
        *(ushort4*)&t[key][c8 + 4] = b;
    }
    __syncthreads();

    const int d  = tid >> 2;
    const int kb = (tid & 3) << 4;
    unsigned short buf[16];
#pragma unroll
    for (int j = 0; j < 16; ++j) buf[j] = t[kb + j][d];
    unsigned short* dst = vt + (size_t)bh * 64 * VT_STRIDE + (size_t)d * VT_STRIDE + kt0 + kb;
#pragma unroll
    for (int j = 0; j < 4; ++j)
        *(ushort4*)(dst + j * 4) = *(ushort4*)&buf[j * 4];
}

// ---------------------------------------------------------------------------
// MFMA flash attention v5b: round-5 passing structure + low-risk softmax diet:
//   - exp2-domain (QSCALE folds log2e; fexp2 = guarded builtin, no asm)
//   - THR=0 defer-rescale -> bit-identical skip of alpha path (wave-uniform)
//   - deferred l-reduction: per-lane partials, one 16-lane reduce in epilogue
//   - P-publish: round-5 proven f2bf path (NO hand-written cvt_pk asm — m240)
// 8 waves x 16 q-rows, dbuf K/V staging, per-tile vmcnt(0)+barrier pipeline.
// ---------------------------------------------------------------------------
__global__ __launch_bounds__(512, 4)
void attn_mfma2(const unsigned short* __restrict__ qhi_g, const unsigned short* __restrict__ qlo_g,
                const unsigned short* __restrict__ khi_g, const unsigned short* __restrict__ klo_g,
                const unsigned short* __restrict__ vt_g,
                unsigned short* __restrict__ Ohi, unsigned short* __restrict__ Olo)
{
    __shared__ unsigned short Khl[2][64 * 64];   // K hi  [key][d], chunk-swizzled
    __shared__ unsigned short Kll[2][64 * 64];   // K lo
    __shared__ unsigned short Vtl[2][64 * 64];   // V^T hi [d][key], chunk-swizzled
    __shared__ unsigned short Pl[128 * 64];      // P [q][key], elementwise-swizzled

    const int tid  = threadIdx.x;
    const int wave = tid >> 6;      // 0..7, each owns 16 q-rows
    const int lane = tid & 63;
    const int lm   = lane & 15;
    const int quad = lane >> 4;
    const int bh   = blockIdx.x;
    const int q0   = blockIdx.y * 128;
    const int b    = bh >> 4;
    const int h    = bh & 15;

    const unsigned short* Qh  = qhi_g + (size_t)bh * N_TOK * 64;
    const unsigned short* Ql  = qlo_g + (size_t)bh * N_TOK * 64;
    const unsigned short* Khb = khi_g + (size_t)bh * N_TOK * 64;
    const unsigned short* Klb = klo_g + (size_t)bh * N_TOK * 64;
    const unsigned short* Vtb = vt_g  + (size_t)bh * 64 * VT_STRIDE;

#define STAGE(bs, kt0_) do {                                                     \
    const int r_  = tid >> 3;                                                    \
    const int qs_ = tid & 7;                                                     \
    const int sw_ = (qs_ ^ (r_ & 7)) << 3;                                       \
    const int ldsoff_ = wave * 512;                                              \
    const int gk_ = min((kt0_) + r_, N_TOK - 1);                                 \
    __builtin_amdgcn_global_load_lds(                                            \
        (__attribute__((address_space(1))) void*)(Khb + (size_t)gk_ * 64 + sw_), \
        (__attribute__((address_space(3))) void*)&Khl[bs][ldsoff_], 16, 0, 0);   \
    __builtin_amdgcn_global_load_lds(                                            \
        (__attribute__((address_space(1))) void*)(Klb + (size_t)gk_ * 64 + sw_), \
        (__attribute__((address_space(3))) void*)&Kll[bs][ldsoff_], 16, 0, 0);   \
    __builtin_amdgcn_global_load_lds(                                            \
        (__attribute__((address_space(1))) void*)(Vtb + (size_t)r_ * VT_STRIDE + (kt0_) + sw_), \
        (__attribute__((address_space(3))) void*)&Vtl[bs][ldsoff_], 16, 0, 0);   \
} while (0)

    // ---- prologue: start tile-0 staging, then Q loads overlap its latency ----
    STAGE(0, 0);

    bf16x8 qh[2], ql[2];
    {
        int row = q0 + wave * 16 + lm;
        if (row > N_TOK - 1) row = N_TOK - 1;
#pragma unroll
        for (int s = 0; s < 2; ++s) {
            const size_t off = (size_t)row * 64 + s * 32 + quad * 8;
            qh[s] = *(const bf16x8*)&Qh[off];
            ql[s] = *(const bf16x8*)&Ql[off];
        }
    }

    f32x4 o[4];
    float m_i[4], lp[4];       // lp = per-lane PARTIAL l (16-lane reduce deferred)
#pragma unroll
    for (int r = 0; r < 4; ++r) {
        m_i[r] = -FLT_MAX;
        lp[r]  = 0.f;
        o[r] = (f32x4){0.f, 0.f, 0.f, 0.f};
    }

    asm volatile("s_waitcnt vmcnt(0)\n\ts_barrier" ::: "memory");

    for (int kt = 0; kt < 17; ++kt) {
        const int kt0 = kt * 64;
        const int cur = kt & 1;

        // ---- prefetch next tile into the other buffer (stays in flight) ----
        if (kt < 16) STAGE(cur ^ 1, kt0 + 64);

        // ---- QK^T: S[16 q][64 key] per wave, from buf[cur] ----
        f32x4 s_acc[4];
#pragma unroll
        for (int ct = 0; ct < 4; ++ct)
            s_acc[ct] = (f32x4){0.f, 0.f, 0.f, 0.f};

#pragma unroll
        for (int ct = 0; ct < 4; ++ct) {
            const int krow = ct * 16 + lm;
#pragma unroll
            for (int s = 0; s < 2; ++s) {
                const int chunk = ((s * 4 + quad) ^ (krow & 7)) << 3;
                const bf16x8 kbh = *(const bf16x8*)&Khl[cur][krow * 64 + chunk];
                const bf16x8 kbl = *(const bf16x8*)&Kll[cur][krow * 64 + chunk];
                s_acc[ct] = __builtin_amdgcn_mfma_f32_16x16x32_bf16(qh[s], kbh, s_acc[ct], 0, 0, 0);
                s_acc[ct] = __builtin_amdgcn_mfma_f32_16x16x32_bf16(qh[s], kbl, s_acc[ct], 0, 0, 0);
                s_acc[ct] = __builtin_amdgcn_mfma_f32_16x16x32_bf16(ql[s], kbh, s_acc[ct], 0, 0, 0);
            }
        }

        // ---- mask OOB keys (last tile only) ----
        if (kt0 + 64 > N_TOK) {
#pragma unroll
            for (int ct = 0; ct < 4; ++ct) {
                if (kt0 + ct * 16 + lm >= N_TOK) {
#pragma unroll
                    for (int r = 0; r < 4; ++r) s_acc[ct][r] = -FLT_MAX;
                }
            }
        }

        // ---- online softmax (exp2 domain, defer-rescale) + publish P ----
#pragma unroll
        for (int r = 0; r < 4; ++r) {
            float mt = fmaxf(fmaxf(s_acc[0][r], s_acc[1][r]),
                             fmaxf(s_acc[2][r], s_acc[3][r]));
            mt = fmaxf(mt, __shfl_xor(mt, 1));
            mt = fmaxf(mt, __shfl_xor(mt, 2));
            mt = fmaxf(mt, __shfl_xor(mt, 4));
            mt = fmaxf(mt, __shfl_xor(mt, 8));
            // THR=0 defer: skip iff no row of this wave got a new max
            // (then alpha==1 exactly -> bit-identical to the full path).
            if (!__all(mt <= m_i[r])) {
                const float mnew  = fmaxf(m_i[r], mt);
                const float alpha = fexp2(m_i[r] - mnew);
                lp[r] *= alpha;
#pragma unroll
                for (int dt = 0; dt < 4; ++dt) o[dt][r] *= alpha;
                m_i[r] = mnew;
            }
            const float mloc = m_i[r];
            float pv[4];
#pragma unroll
            for (int ct = 0; ct < 4; ++ct) pv[ct] = fexp2(s_acc[ct][r] - mloc);
            lp[r] += (pv[0] + pv[1]) + (pv[2] + pv[3]);
            const int prow = wave * 16 + quad * 4 + r;
#pragma unroll
            for (int ct = 0; ct < 4; ++ct) {
                const int col = ct * 16 + lm;
                const int idx = prow * 64 + ((((col >> 3) ^ (prow & 7)) << 3) | (col & 7));
                Pl[idx] = f2bf(pv[ct]);
            }
        }

        // ---- PV: o += P @ V^T  (wave-private P; V hi only -> 1 MFMA) ----
#pragma unroll
        for (int ks = 0; ks < 2; ++ks) {
            const int prow = wave * 16 + lm;
            const int chunk = ((ks * 4 + quad) ^ (prow & 7)) << 3;
            const bf16x8 pf = *(const bf16x8*)&Pl[prow * 64 + chunk];
#pragma unroll
            for (int dt = 0; dt < 4; ++dt) {
                const int vrow = dt * 16 + lm;
                const int chunkv = ((ks * 4 + quad) ^ (vrow & 7)) << 3;
                const bf16x8 vh = *(const bf16x8*)&Vtl[cur][vrow * 64 + chunkv];
                o[dt] = __builtin_amdgcn_mfma_f32_16x16x32_bf16(pf, vh, o[dt], 0, 0, 0);
            }
        }

        // ---- single per-tile sync: prefetch landed + all frag reads done ----
        asm volatile("s_waitcnt vmcnt(0)\n\ts_barrier" ::: "memory");
    }
#undef STAGE

    // ---- epilogue: finish l reduce, normalize, bf16 hi/lo split, store ----
#pragma unroll
    for (int r = 0; r < 4; ++r) {
        float l = lp[r];
        l += __shfl_xor(l, 1);
        l += __shfl_xor(l, 2);
        l += __shfl_xor(l, 4);
        l += __shfl_xor(l, 8);
        const int gq = q0 + wave * 16 + quad * 4 + r;
        if (gq >= N_TOK) continue;
        const float inv = 1.0f / l;
        const size_t base = (((size_t)(b * N_TOK + gq)) * H_ + h) * D_;
#pragma unroll
        for (int dt = 0; dt < 4; ++dt) {
            const float val = o[dt][r] * inv;
            const unsigned short hb = f2bf(val);
            Ohi[base + dt * 16 + lm] = hb;
            Olo[base + dt * 16 + lm] = f2bf(val - bf2f(hb));
        }
    }
}

// ---------------------------------------------------------------------------
// ws = EXACTLY 4 fp32 slabs (269,746,176 B — proven budget). Map:
//   slab1: qhi/qlo   (GEMM1 fused out)  — dead after attn
//   slab2: khi/klo   (GEMM1 fused out)  — dead after attn -> wp_hi/wp_lo
//   slab3: vhi bf16  (GEMM1 fused out)  — dead after v_transpose
//   slab4: x_hi/x_lo (pre-GEMM1)        — dead after GEMM1 -> attn_hi/attn_lo
//   d_out: wq_hi/wq_lo -> vthi (after GEMM1) -> final out (GEMM2)
// ---------------------------------------------------------------------------
extern "C" void kernel_launch(void* const* d_in, const int* in_sizes, int n_in,
                              void* d_out, int out_size, void* d_ws, size_t ws_size,
                              hipStream_t stream)
{
    const float* x        = (const float*)d_in[0];
    const float* rope_sin = (const float*)d_in[1];
    const float* rope_cos = (const float*)d_in[2];
    const float* W_qkv    = (const float*)d_in[3];
    const float* b_qkv    = (const float*)d_in[4];
    const float* W_proj   = (const float*)d_in[5];
    const float* b_proj   = (const float*)d_in[6];
    float* out = (float*)d_out;

    float* slab1 = (float*)d_ws;
    float* slab2 = slab1 + HEAD_SLAB;
    float* slab3 = slab1 + 2 * HEAD_SLAB;
    float* slab4 = slab1 + 3 * HEAD_SLAB;

    unsigned short* x_hi = (unsigned short*)slab4;
    unsigned short* x_lo = x_hi + HEAD_SLAB;
    unsigned short* wq_hi = (unsigned short*)d_out;
    unsigned short* wq_lo = wq_hi + (size_t)3 * C_ * C_;

    unsigned short* qhi = (unsigned short*)slab1;
    unsigned short* qlo = qhi + HEAD_SLAB;
    unsigned short* khi = (unsigned short*)slab2;
    unsigned short* klo = khi + HEAD_SLAB;
    unsigned short* vhi = (unsigned short*)slab3;

    unsigned short* vthi = (unsigned short*)d_out;           // after GEMM1
    unsigned short* attn_hi = (unsigned short*)slab4;        // after GEMM1 (x dead)
    unsigned short* attn_lo = attn_hi + HEAD_SLAB;
    unsigned short* wp_hi = (unsigned short*)slab2;          // after attn (k dead)
    unsigned short* wp_lo = wp_hi + (size_t)C_ * C_;

    // 0) fp32 -> bf16 hi/lo splits for x and W_qkv
    {
        const int n4x = M_ROWS * C_ / 4;
        split_kernel<<<(n4x + 255) / 256, 256, 0, stream>>>(x, x_hi, x_lo, n4x);
        const int n4q = 3 * C_ * C_ / 4;
        split_kernel<<<(n4q + 255) / 256, 256, 0, stream>>>(W_qkv, wq_hi, wq_lo, n4q);
    }
    // 1) QKV projection + fused bias/RoPE/split -> qhi/qlo, khi/klo, vhi
    {
        dim3 grid(3 * C_ / 256, (M_ROWS + 255) / 256);
        gemm_mfma8<<<grid, 512, 0, stream>>>(x_hi, x_lo, wq_hi, wq_lo, b_qkv,
                                             out, M_ROWS, 3 * C_, C_, 1,
                                             rope_sin, rope_cos,
                                             qhi, qlo, khi, klo, vhi);
    }
    // 2) V bf16-hi -> transposed slab (in d_out; wq splits now dead)
    {
        dim3 grid(17, B_ * H_);
        v_transpose<<<grid, 256, 0, stream>>>(vhi, vthi);
    }
    // 3) MFMA flash attention (8-wave) -> attn hi/lo bf16 [B,N,H,D] in slab4
    {
        dim3 grid(B_ * H_, (N_TOK + 127) / 128);   // x=bh: XCD locality
        attn_mfma2<<<grid, 512, 0, stream>>>(qhi, qlo, khi, klo, vthi,
                                             attn_hi, attn_lo);
    }
    // 3b) split W_proj into dead k-slab
    {
        const int n4p = C_ * C_ / 4;
        split_kernel<<<(n4p + 255) / 256, 256, 0, stream>>>(W_proj, wp_hi, wp_lo, n4p);
    }
    // 4) Output projection (MFMA, 256x256 pipelined) -> d_out (overwrites vthi)
    {
        dim3 grid(C_ / 256, (M_ROWS + 255) / 256);
        gemm_mfma8<<<grid, 512, 0, stream>>>(attn_hi, attn_lo, wp_hi, wp_lo, b_proj,
                                             out, M_ROWS, C_, C_, 0,
                                             nullptr, nullptr,
                                             nullptr, nullptr, nullptr, nullptr, nullptr);
    }
}